// Round 3
// baseline (1030.439 us; speedup 1.0000x reference)
//
#include <hip/hip_runtime.h>

// R-GCN (3 layers) on MI355X — Round 3: aggregation FUSED into the GEMM.
// Per 128-row M-tile block, loop over units = (relation-or-root, k-half):
//   stage B 128x128 weights via global_load_lds (inverse-swizzled source),
//   gather per-(node,rel) mean rows from L2/L3-resident h into swizzled LDS A,
//   then 4 x (ds_read_b128 frags + 16 MFMA). No agg buffer, no agg kernels.

#define DEVI __device__ __forceinline__

constexpr int NN    = 50000;
constexpr int EE    = 800000;
constexpr int RREL  = 8;
constexpr int NRSEG = NN * RREL;          // 400000

using u16 = unsigned short;
using u32 = unsigned int;
using u64 = unsigned long long;

typedef short short8 __attribute__((ext_vector_type(8)));
typedef float f32x4  __attribute__((ext_vector_type(4)));

DEVI float bf2f(u32 u){ union{u32 i; float f;} x; x.i = u << 16; return x.f; }
DEVI u16   f2b(float f){ u32 u = __float_as_uint(f); u32 r = u + 0x7fffu + ((u >> 16) & 1u); return (u16)(r >> 16); }

typedef const __attribute__((address_space(1))) u32 gas_u32;
typedef __attribute__((address_space(3))) u32       las_u32;
DEVI void gload16(const void* g, void* l){
  __builtin_amdgcn_global_load_lds((gas_u32*)(u64)g, (las_u32*)(u64)l, 16, 0, 0);
}

// ---------------- prep kernels ----------------

__global__ void count_k(const int* __restrict__ dst, const int* __restrict__ et, int* __restrict__ cnt){
  int e = blockIdx.x * 256 + threadIdx.x;
  if(e < EE) atomicAdd(&cnt[dst[e] * RREL + et[e]], 1);
}

constexpr int SCAN_E = 8;
constexpr int CHUNK  = 2048;
constexpr int NB     = (NRSEG + CHUNK - 1) / CHUNK;   // 196

__global__ void scan1_k(const int* __restrict__ cnt, int* __restrict__ bsums){
  __shared__ int sm[256];
  int b = blockIdx.x, t = threadIdx.x;
  int base = b * CHUNK + t * SCAN_E;
  int s = 0;
  #pragma unroll
  for(int j = 0; j < SCAN_E; j++){ int i = base + j; s += (i < NRSEG) ? cnt[i] : 0; }
  sm[t] = s; __syncthreads();
  for(int off = 128; off > 0; off >>= 1){ if(t < off) sm[t] += sm[t + off]; __syncthreads(); }
  if(t == 0) bsums[b] = sm[0];
}

__global__ void scan2_k(int* __restrict__ bsums){
  __shared__ int sm[256];
  int t = threadIdx.x;
  int v = (t < NB) ? bsums[t] : 0;
  sm[t] = v; __syncthreads();
  for(int off = 1; off < 256; off <<= 1){
    int x = (t >= off) ? sm[t - off] : 0; __syncthreads();
    sm[t] += x; __syncthreads();
  }
  if(t < NB) bsums[t] = sm[t] - v;   // exclusive
}

__global__ void scan3_k(const int* __restrict__ cnt, const int* __restrict__ bsums, int* __restrict__ offs){
  __shared__ int sm[256];
  int b = blockIdx.x, t = threadIdx.x;
  int base = b * CHUNK + t * SCAN_E;
  int loc[SCAN_E]; int run = 0;
  #pragma unroll
  for(int j = 0; j < SCAN_E; j++){ int i = base + j; int c = (i < NRSEG) ? cnt[i] : 0; loc[j] = run; run += c; }
  sm[t] = run; __syncthreads();
  for(int off = 1; off < 256; off <<= 1){
    int x = (t >= off) ? sm[t - off] : 0; __syncthreads();
    sm[t] += x; __syncthreads();
  }
  int tb = bsums[b] + sm[t] - run;
  #pragma unroll
  for(int j = 0; j < SCAN_E; j++){ int i = base + j; if(i < NRSEG) offs[i] = tb + loc[j]; }
  if(b == 0 && t == 0) offs[NRSEG] = EE;
}

__global__ void fill_k(const int* __restrict__ src, const int* __restrict__ dst, const int* __restrict__ et,
                       const int* __restrict__ offs, int* __restrict__ fill, int* __restrict__ ssrc){
  int e = blockIdx.x * 256 + threadIdx.x;
  if(e < EE){
    int seg = dst[e] * RREL + et[e];
    int r = atomicAdd(&fill[seg], 1);
    ssrc[offs[seg] + r] = src[e];
  }
}

__global__ void inv_k(const int* __restrict__ cnt, float* __restrict__ inv){
  int i = blockIdx.x * 256 + threadIdx.x;
  if(i < NRSEG){ int c = cnt[i]; inv[i] = 1.0f / (float)(c > 0 ? c : 1); }
}

__global__ void castx_k(const float* __restrict__ x, u16* __restrict__ xb){
  int i = blockIdx.x * 256 + threadIdx.x;
  if(i < NN * 128) xb[i] = f2b(x[i]);
}

// Wp[g][o][i] = bf16( g<R ? W[g][i][o] : root[i][o] )   (transposed: rows contiguous in fin)
__global__ void packw_k(const float* __restrict__ w, const float* __restrict__ root,
                        u16* __restrict__ wp, int FIN, int FOUT){
  int idx = blockIdx.x * 256 + threadIdx.x;
  int tot = (RREL + 1) * FIN * FOUT;
  if(idx < tot){
    int i = idx % FIN;
    int o = (idx / FIN) % FOUT;
    int g = idx / (FIN * FOUT);
    float v = (g < RREL) ? w[((size_t)g * FIN + i) * FOUT + o] : root[(size_t)i * FOUT + o];
    wp[idx] = f2b(v);
  }
}

// ---------------- fused gather + GEMM ----------------
// Units u: g = u/KH (0..7 rel, 8 root), kh = u%KH; KH = FIN/128.
// LDS A,B: 128x128 bf16 each, XOR-swizzled (16B chunk index ^= row&7).

DEVI void acc8(float* a, uint4 v){
  a[0] += bf2f(v.x & 0xffffu); a[1] += bf2f(v.x >> 16);
  a[2] += bf2f(v.y & 0xffffu); a[3] += bf2f(v.y >> 16);
  a[4] += bf2f(v.z & 0xffffu); a[5] += bf2f(v.z >> 16);
  a[6] += bf2f(v.w & 0xffffu); a[7] += bf2f(v.w >> 16);
}

DEVI void storeA(u16* As, int r, int gl, const float* a, float sc){
  uint4 o;
  o.x = (u32)f2b(a[0]*sc) | ((u32)f2b(a[1]*sc) << 16);
  o.y = (u32)f2b(a[2]*sc) | ((u32)f2b(a[3]*sc) << 16);
  o.z = (u32)f2b(a[4]*sc) | ((u32)f2b(a[5]*sc) << 16);
  o.w = (u32)f2b(a[6]*sc) | ((u32)f2b(a[7]*sc) << 16);
  *(uint4*)(As + r * 128 + ((gl ^ (r & 7)) << 3)) = o;
}

template<int FIN, int FOUT, bool HB>
__global__ __launch_bounds__(256)
void fgemm_k(const u16* __restrict__ hb, const int* __restrict__ ssrc,
             const int* __restrict__ offs, const float* __restrict__ inv,
             const u16* __restrict__ wp, const float* __restrict__ bias,
             float* __restrict__ dout, int dcol0, u16* __restrict__ hbout)
{
  constexpr int NT = FOUT / 128;
  constexpr int KH = FIN / 128;
  constexpr int NU = 9 * KH;
  __shared__ u16 As[128 * 128];
  __shared__ u16 Bs[128 * 128];
  const int bm  = (int)blockIdx.x / NT;
  const int bn  = (int)blockIdx.x % NT;
  const int tid = threadIdx.x;
  const int wid = tid >> 6, lane = tid & 63;
  const int wm  = wid >> 1, wn = wid & 1;
  const int gl  = tid & 15;          // lane within 16-lane gather group
  const int grp = tid >> 4;          // 16 groups; group handles rows grp*8..+7
  const int nb  = bm * 128;

  f32x4 acc[4][4] = {};

  for(int u = 0; u < NU; u++){
    const int g  = u / KH;
    const int kh = u % KH;
    const bool isRoot = (g == RREL);

    // ---- stage B first (async gload_lds overlaps the gather below) ----
    #pragma unroll
    for(int rnd = 0; rnd < 8; rnd++){
      int sb = rnd * 256 + wid * 64;               // wave-uniform slot base
      int s  = sb + lane;
      int row = s >> 4;
      int c   = (s & 15) ^ (row & 7);              // inverse swizzle on source
      const u16* gb = wp + ((size_t)g * FOUT + bn * 128 + row) * FIN + kh * 128 + c * 8;
      gload16(gb, Bs + sb * 8);
    }

    // ---- gather-mean A rows into swizzled LDS ----
    if(isRoot){
      #pragma unroll
      for(int j = 0; j < 8; j++){
        int r = grp * 8 + j;
        int node = nb + r; node = node < NN ? node : NN - 1;
        uint4 v = *(const uint4*)(hb + (size_t)node * FIN + kh * 128 + gl * 8);
        float a[8] = {0,0,0,0,0,0,0,0};
        acc8(a, v);
        storeA(As, r, gl, a, 1.0f);
      }
    } else {
      #pragma unroll
      for(int jp = 0; jp < 4; jp++){
        int r0 = grp * 8 + jp * 2, r1 = r0 + 1;
        int n0 = nb + r0; n0 = n0 < NN ? n0 : NN - 1;
        int n1 = nb + r1; n1 = n1 < NN ? n1 : NN - 1;
        int s0 = n0 * RREL + g, s1 = n1 * RREL + g;
        int c0 = offs[s0], e0 = offs[s0 + 1];
        int c1 = offs[s1], e1 = offs[s1 + 1];
        float sc0 = inv[s0], sc1 = inv[s1];
        float a0[8] = {0,0,0,0,0,0,0,0};
        float a1[8] = {0,0,0,0,0,0,0,0};
        while(c0 < e0 || c1 < e1){          // dual-row lockstep for MLP
          bool p0 = c0 < e0, p1 = c1 < e1;
          uint4 v0, v1;
          if(p0) v0 = *(const uint4*)(hb + (size_t)ssrc[c0] * FIN + kh * 128 + gl * 8);
          if(p1) v1 = *(const uint4*)(hb + (size_t)ssrc[c1] * FIN + kh * 128 + gl * 8);
          if(p0){ acc8(a0, v0); c0++; }
          if(p1){ acc8(a1, v1); c1++; }
        }
        storeA(As, r0, gl, a0, sc0);
        storeA(As, r1, gl, a1, sc1);
      }
    }
    __syncthreads();                    // drains vmcnt (B) + lgkm (A writes)

    // ---- compute: 4 K-substeps x 16 MFMA ----
    #pragma unroll
    for(int ss = 0; ss < 4; ss++){
      short8 af[4], bf4[4];
      #pragma unroll
      for(int m = 0; m < 4; m++){
        int r = wm * 64 + m * 16 + (lane & 15);
        int c = ss * 4 + (lane >> 4);
        af[m] = *(const short8*)(As + r * 128 + ((c ^ (r & 7)) << 3));
      }
      #pragma unroll
      for(int n = 0; n < 4; n++){
        int r = wn * 64 + n * 16 + (lane & 15);
        int c = ss * 4 + (lane >> 4);
        bf4[n] = *(const short8*)(Bs + r * 128 + ((c ^ (r & 7)) << 3));
      }
      #pragma unroll
      for(int m = 0; m < 4; m++)
        #pragma unroll
        for(int n = 0; n < 4; n++)
          acc[m][n] = __builtin_amdgcn_mfma_f32_16x16x32_bf16(af[m], bf4[n], acc[m][n], 0, 0, 0);
    }
    __syncthreads();                    // before next unit overwrites LDS
  }

  // epilogue; C/D layout: col = lane&15, row = (lane>>4)*4 + reg   [m89-verified]
  #pragma unroll
  for(int m = 0; m < 4; m++){
    #pragma unroll
    for(int j = 0; j < 4; j++){
      int grow = bm * 128 + wm * 64 + m * 16 + (lane >> 4) * 4 + j;
      if(grow >= NN) continue;
      #pragma unroll
      for(int n = 0; n < 4; n++){
        int gcol = bn * 128 + wn * 64 + n * 16 + (lane & 15);
        float v = acc[m][n][j];
        v += bias[gcol];
        v = v > 0.f ? v : expm1f(v);
        dout[(size_t)grow * 512 + dcol0 + gcol] = v;
        if constexpr(HB) hbout[(size_t)grow * FOUT + gcol] = f2b(v);
      }
    }
  }
}

// ---------------- host ----------------

extern "C" void kernel_launch(void* const* d_in, const int* in_sizes, int n_in,
                              void* d_out, int out_size, void* d_ws, size_t ws_size,
                              hipStream_t stream)
{
  const float* x     = (const float*)d_in[0];
  const int*   ei    = (const int*)d_in[1];   // [2, E] int32
  const int*   et    = (const int*)d_in[2];   // [E]
  const float* w1    = (const float*)d_in[3];
  const float* root1 = (const float*)d_in[4];
  const float* b1    = (const float*)d_in[5];
  const float* w2    = (const float*)d_in[6];
  const float* root2 = (const float*)d_in[7];
  const float* b2    = (const float*)d_in[8];
  const float* w3    = (const float*)d_in[9];
  const float* root3 = (const float*)d_in[10];
  const float* b3    = (const float*)d_in[11];
  float* out = (float*)d_out;

  const int* esrc = ei;
  const int* edst = ei + EE;

  char* w = (char*)d_ws;
  auto alloc = [&](size_t bytes)->char*{ char* p = w; w += (bytes + 255) & ~(size_t)255; return p; };
  int*   cnt   = (int*)  alloc((size_t)NRSEG * 4);
  int*   offs  = (int*)  alloc((size_t)(NRSEG + 1) * 4);
  int*   fill  = (int*)  alloc((size_t)NRSEG * 4);
  float* inv   = (float*)alloc((size_t)NRSEG * 4);
  int*   ssrc  = (int*)  alloc((size_t)EE * 4);
  u16*   xb    = (u16*)  alloc((size_t)NN * 128 * 2);
  u16*   h1b   = (u16*)  alloc((size_t)NN * 256 * 2);
  u16*   h2b   = (u16*)  alloc((size_t)NN * 128 * 2);
  u16*   wp1   = (u16*)  alloc((size_t)9 * 256 * 128 * 2);
  u16*   wp2   = (u16*)  alloc((size_t)9 * 256 * 128 * 2);
  u16*   wp3   = (u16*)  alloc((size_t)9 * 128 * 128 * 2);
  int*   bsums = (int*)  alloc(1024 * 4);
  (void)ws_size; (void)in_sizes; (void)n_in; (void)out_size;

  hipMemsetAsync(cnt,  0, (size_t)NRSEG * 4, stream);
  hipMemsetAsync(fill, 0, (size_t)NRSEG * 4, stream);

  count_k<<<(EE + 255) / 256, 256, 0, stream>>>(edst, et, cnt);
  scan1_k<<<NB, 256, 0, stream>>>(cnt, bsums);
  scan2_k<<<1, 256, 0, stream>>>(bsums);
  scan3_k<<<NB, 256, 0, stream>>>(cnt, bsums, offs);
  fill_k<<<(EE + 255) / 256, 256, 0, stream>>>(esrc, edst, et, offs, fill, ssrc);
  inv_k<<<(NRSEG + 255) / 256, 256, 0, stream>>>(cnt, inv);
  castx_k<<<(NN * 128 + 255) / 256, 256, 0, stream>>>(x, xb);

  packw_k<<<(9 * 128 * 256 + 255) / 256, 256, 0, stream>>>(w1, root1, wp1, 128, 256);
  packw_k<<<(9 * 256 * 128 + 255) / 256, 256, 0, stream>>>(w2, root2, wp2, 256, 128);
  packw_k<<<(9 * 128 * 128 + 255) / 256, 256, 0, stream>>>(w3, root3, wp3, 128, 128);

  const int MT = (NN + 127) / 128;   // 391

  // Layer 1: fin=128, fout=256 (NT=2)
  fgemm_k<128, 256, true><<<MT * 2, 256, 0, stream>>>(
      xb, ssrc, offs, inv, wp1, b1, out, 0, h1b);
  // Layer 2: fin=256, fout=128 — single pass, 18 units
  fgemm_k<256, 128, true><<<MT, 256, 0, stream>>>(
      h1b, ssrc, offs, inv, wp2, b2, out, 256, h2b);
  // Layer 3: fin=128, fout=128
  fgemm_k<128, 128, false><<<MT, 256, 0, stream>>>(
      h2b, ssrc, offs, inv, wp3, b3, out, 384, nullptr);
}

// Round 4
// 470.627 us; speedup vs baseline: 2.1895x; 2.1895x over previous
//
#include <hip/hip_runtime.h>

// R-GCN (3 layers) on MI355X — Round 4: back to split agg+gemm (round-2
// structure, which passed with 0 LDS conflicts), but GEMM now uses 8-wave
// (512-thread) blocks on 128-row tiles: 2x resident waves per CU (round-2
// gemm was grid-bound at 19% occupancy), and L1 is a single 128x256 tile
// (NT=1) so the 100MB agg buffer is read once instead of twice.

#define DEVI __device__ __forceinline__

constexpr int NN    = 50000;
constexpr int EE    = 800000;
constexpr int RREL  = 8;
constexpr int NRSEG = NN * RREL;          // 400000

using u16 = unsigned short;
using u32 = unsigned int;
using u64 = unsigned long long;

typedef short short8 __attribute__((ext_vector_type(8)));
typedef float f32x4  __attribute__((ext_vector_type(4)));

DEVI float bf2f(u32 u){ union{u32 i; float f;} x; x.i = u << 16; return x.f; }
DEVI u16   f2b(float f){ u32 u = __float_as_uint(f); u32 r = u + 0x7fffu + ((u >> 16) & 1u); return (u16)(r >> 16); }

typedef const __attribute__((address_space(1))) u32 gas_u32;
typedef __attribute__((address_space(3))) u32       las_u32;
DEVI void gload16(const void* g, void* l){
  __builtin_amdgcn_global_load_lds((gas_u32*)(u64)g, (las_u32*)(u64)l, 16, 0, 0);
}

// ---------------- prep kernels ----------------

__global__ void count_k(const int* __restrict__ dst, const int* __restrict__ et, int* __restrict__ cnt){
  int e = blockIdx.x * 256 + threadIdx.x;
  if(e < EE) atomicAdd(&cnt[dst[e] * RREL + et[e]], 1);
}

constexpr int SCAN_E = 8;
constexpr int CHUNK  = 2048;
constexpr int NB     = (NRSEG + CHUNK - 1) / CHUNK;   // 196

__global__ void scan1_k(const int* __restrict__ cnt, int* __restrict__ bsums){
  __shared__ int sm[256];
  int b = blockIdx.x, t = threadIdx.x;
  int base = b * CHUNK + t * SCAN_E;
  int s = 0;
  #pragma unroll
  for(int j = 0; j < SCAN_E; j++){ int i = base + j; s += (i < NRSEG) ? cnt[i] : 0; }
  sm[t] = s; __syncthreads();
  for(int off = 128; off > 0; off >>= 1){ if(t < off) sm[t] += sm[t + off]; __syncthreads(); }
  if(t == 0) bsums[b] = sm[0];
}

__global__ void scan2_k(int* __restrict__ bsums){
  __shared__ int sm[256];
  int t = threadIdx.x;
  int v = (t < NB) ? bsums[t] : 0;
  sm[t] = v; __syncthreads();
  for(int off = 1; off < 256; off <<= 1){
    int x = (t >= off) ? sm[t - off] : 0; __syncthreads();
    sm[t] += x; __syncthreads();
  }
  if(t < NB) bsums[t] = sm[t] - v;   // exclusive
}

__global__ void scan3_k(const int* __restrict__ cnt, const int* __restrict__ bsums, int* __restrict__ offs){
  __shared__ int sm[256];
  int b = blockIdx.x, t = threadIdx.x;
  int base = b * CHUNK + t * SCAN_E;
  int loc[SCAN_E]; int run = 0;
  #pragma unroll
  for(int j = 0; j < SCAN_E; j++){ int i = base + j; int c = (i < NRSEG) ? cnt[i] : 0; loc[j] = run; run += c; }
  sm[t] = run; __syncthreads();
  for(int off = 1; off < 256; off <<= 1){
    int x = (t >= off) ? sm[t - off] : 0; __syncthreads();
    sm[t] += x; __syncthreads();
  }
  int tb = bsums[b] + sm[t] - run;
  #pragma unroll
  for(int j = 0; j < SCAN_E; j++){ int i = base + j; if(i < NRSEG) offs[i] = tb + loc[j]; }
  if(b == 0 && t == 0) offs[NRSEG] = EE;
}

__global__ void fill_k(const int* __restrict__ src, const int* __restrict__ dst, const int* __restrict__ et,
                       const int* __restrict__ offs, int* __restrict__ fill, int* __restrict__ ssrc){
  int e = blockIdx.x * 256 + threadIdx.x;
  if(e < EE){
    int seg = dst[e] * RREL + et[e];
    int r = atomicAdd(&fill[seg], 1);
    ssrc[offs[seg] + r] = src[e];
  }
}

__global__ void inv_k(const int* __restrict__ cnt, float* __restrict__ inv){
  int i = blockIdx.x * 256 + threadIdx.x;
  if(i < NRSEG){ int c = cnt[i]; inv[i] = 1.0f / (float)(c > 0 ? c : 1); }
}

__global__ void castx_k(const float* __restrict__ x, u16* __restrict__ xb){
  int i = blockIdx.x * 256 + threadIdx.x;
  if(i < NN * 128) xb[i] = f2b(x[i]);
}

// Wp[g][o][i] = bf16( g<R ? W[g][i][o] : root[i][o] )   (transposed: rows contiguous in fin)
__global__ void packw_k(const float* __restrict__ w, const float* __restrict__ root,
                        u16* __restrict__ wp, int FIN, int FOUT){
  int idx = blockIdx.x * 256 + threadIdx.x;
  int tot = (RREL + 1) * FIN * FOUT;
  if(idx < tot){
    int i = idx % FIN;
    int o = (idx / FIN) % FOUT;
    int g = idx / (FIN * FOUT);
    float v = (g < RREL) ? w[((size_t)g * FIN + i) * FOUT + o] : root[(size_t)i * FOUT + o];
    wp[idx] = f2b(v);
  }
}

// ---------------- aggregation: lane-group (FIN/8 lanes) per segment ----------------

DEVI void acc8(float* a, uint4 v){
  a[0] += bf2f(v.x & 0xffffu); a[1] += bf2f(v.x >> 16);
  a[2] += bf2f(v.y & 0xffffu); a[3] += bf2f(v.y >> 16);
  a[4] += bf2f(v.z & 0xffffu); a[5] += bf2f(v.z >> 16);
  a[6] += bf2f(v.w & 0xffffu); a[7] += bf2f(v.w >> 16);
}

template<int FIN, int RSUB>
__global__ __launch_bounds__(256)
void agg_k(const u16* __restrict__ hb, const int* __restrict__ ssrc,
           const int* __restrict__ offs, const float* __restrict__ inv,
           u16* __restrict__ agg, int r0)
{
  constexpr int G = FIN / 8;                 // lanes per group: 16 or 32
  const int gl  = threadIdx.x & (G - 1);     // lane within group
  int gid = (int)((blockIdx.x * blockDim.x + threadIdx.x) / G);
  const int ng = (int)((gridDim.x * blockDim.x) / G);
  const int S = NN * RSUB;
  for(int s = gid; s < S; s += ng){
    int n = s / RSUB, rr = s - n * RSUB;
    int seg = n * RREL + r0 + rr;
    int beg = offs[seg], end = offs[seg + 1];
    float sc = inv[seg];
    float acc[8];
    #pragma unroll
    for(int i = 0; i < 8; i++) acc[i] = 0.f;
    int e = beg;
    for(; e + 2 <= end; e += 2){
      int s0 = ssrc[e], s1 = ssrc[e + 1];
      uint4 v0 = ((const uint4*)(hb + (size_t)s0 * FIN))[gl];
      uint4 v1 = ((const uint4*)(hb + (size_t)s1 * FIN))[gl];
      acc8(acc, v0);
      acc8(acc, v1);
    }
    if(e < end){
      uint4 v0 = ((const uint4*)(hb + (size_t)ssrc[e] * FIN))[gl];
      acc8(acc, v0);
    }
    uint4 o;
    o.x = (u32)f2b(acc[0] * sc) | ((u32)f2b(acc[1] * sc) << 16);
    o.y = (u32)f2b(acc[2] * sc) | ((u32)f2b(acc[3] * sc) << 16);
    o.z = (u32)f2b(acc[4] * sc) | ((u32)f2b(acc[5] * sc) << 16);
    o.w = (u32)f2b(acc[6] * sc) | ((u32)f2b(acc[7] * sc) << 16);
    ((uint4*)(agg + (size_t)n * 1024 + rr * FIN))[gl] = o;
  }
}

// ---------------- GEMM: 128xFOUT tile, 8 waves (512 thr), BK=32, mfma 16x16x32 ----------------
// Wave layout: FOUT=256 -> 2x4 (wave tile 64x64, acc[4][4]);
//              FOUT=128 -> 4x2 (wave tile 32x64, acc[2][4]).
// A groups: NAGG from agg[N,1024] (+ optional root). B: packed [g][FOUT][FIN].
// EPI: 0 = raw partial store, 1 = bias+ELU (+hb), 2 = add partial + bias + ELU (+hb)

template<int FIN, int NAGG, bool ROOT, int EPI, int FOUT>
__global__ __launch_bounds__(512)
void gemm_k(const u16* __restrict__ Aagg, const u16* __restrict__ Aroot,
            const u16* __restrict__ Wagg, const u16* __restrict__ Wroot,
            const float* __restrict__ bias, float* __restrict__ dout,
            u16* __restrict__ hbout)
{
  static_assert(FIN % 32 == 0, "");
  constexpr int KSG = FIN / 32;
  constexpr int NG  = NAGG + (ROOT ? 1 : 0);
  constexpr int NKS = NG * KSG;
  constexpr int LDA = NAGG * FIN;        // = 1024 in all uses
  constexpr int WN    = (FOUT == 256) ? 4 : 2;
  constexpr int WROWS = 128 / (8 / WN);  // 64 or 32
  constexpr int MREP  = WROWS / 16;      // 4 or 2
  constexpr int ASL = 512;               // A 16B slots (128 rows x 4)
  constexpr int BSL = FOUT * 4;          // B 16B slots
  __shared__ u16 lds[2][(ASL + BSL) * 8];
  const int bm  = (int)blockIdx.x;
  const int tid = threadIdx.x;
  const int wid = tid >> 6, lane = tid & 63;
  const int wm  = wid / WN, wn = wid % WN;

  auto stage = [&](int ks, u16* l){
    u16* lA = l;
    u16* lB = l + ASL * 8;
    int g    = ks / KSG;
    int koff = (ks - g * KSG) * 32;
    bool isRoot = ROOT && (g == NAGG);
    {
      int sb = wid * 64;                 // wave-uniform slot base, A: slots 0..511
      int s  = sb + lane;
      int pair = s >> 3, cs = s & 7;
      int c    = cs ^ (pair & 7);
      int row  = pair * 2 + (c >> 2);
      int k8   = c & 3;
      int kk   = koff + k8 * 8;
      int rowg = bm * 128 + row; rowg = rowg < NN ? rowg : NN - 1;
      const u16* ga = isRoot ? (Aroot + (size_t)rowg * FIN + kk)
                             : (Aagg + (size_t)rowg * LDA + g * FIN + kk);
      gload16(ga, lA + sb * 8);
    }
    #pragma unroll
    for(int rnd = 0; rnd < BSL / 512; rnd++){
      int sb = rnd * 512 + wid * 64;     // B: slots 0..BSL-1
      int s  = sb + lane;
      int pair = s >> 3, cs = s & 7;
      int c    = cs ^ (pair & 7);
      int row  = pair * 2 + (c >> 2);    // 0..FOUT-1
      int k8   = c & 3;
      int kk   = koff + k8 * 8;
      const u16* gb = isRoot ? (Wroot + (size_t)row * FIN + kk)
                             : (Wagg + ((size_t)g * FOUT + row) * FIN + kk);
      gload16(gb, lB + sb * 8);
    }
  };

  auto ldfrag = [&](const u16* buf, int row, int k8){
    int pair = row >> 1;
    int c    = ((row & 1) << 2) + k8;
    int cs   = c ^ (pair & 7);
    return *(const short8*)(buf + pair * 64 + cs * 8);
  };

  f32x4 acc[MREP][4] = {};

  stage(0, (u16*)lds[0]);
  __syncthreads();
  for(int ks = 0; ks < NKS; ks++){
    int cur = ks & 1;
    if(ks + 1 < NKS) stage(ks + 1, (u16*)lds[cur ^ 1]);
    const u16* lA = (const u16*)lds[cur];
    const u16* lB = lA + ASL * 8;
    short8 af[MREP], bf4[4];
    #pragma unroll
    for(int m = 0; m < MREP; m++) af[m] = ldfrag(lA, wm * WROWS + m * 16 + (lane & 15), lane >> 4);
    #pragma unroll
    for(int n = 0; n < 4; n++) bf4[n] = ldfrag(lB, wn * 64 + n * 16 + (lane & 15), lane >> 4);
    #pragma unroll
    for(int m = 0; m < MREP; m++)
      #pragma unroll
      for(int n = 0; n < 4; n++)
        acc[m][n] = __builtin_amdgcn_mfma_f32_16x16x32_bf16(af[m], bf4[n], acc[m][n], 0, 0, 0);
    __syncthreads();
  }

  // epilogue; C/D layout: col = lane&15, row = (lane>>4)*4 + reg   [m89-verified]
  #pragma unroll
  for(int m = 0; m < MREP; m++){
    #pragma unroll
    for(int j = 0; j < 4; j++){
      int grow = bm * 128 + wm * WROWS + m * 16 + (lane >> 4) * 4 + j;
      if(grow >= NN) continue;
      #pragma unroll
      for(int n = 0; n < 4; n++){
        int gcol = wn * 64 + n * 16 + (lane & 15);
        float v = acc[m][n][j];
        if constexpr(EPI == 0){
          dout[(size_t)grow * 512 + gcol] = v;
        } else {
          if constexpr(EPI == 2) v += dout[(size_t)grow * 512 + gcol];
          v += bias[gcol];
          v = v > 0.f ? v : expm1f(v);
          dout[(size_t)grow * 512 + gcol] = v;
          if(hbout) hbout[(size_t)grow * FOUT + gcol] = f2b(v);
        }
      }
    }
  }
}

// ---------------- host ----------------

extern "C" void kernel_launch(void* const* d_in, const int* in_sizes, int n_in,
                              void* d_out, int out_size, void* d_ws, size_t ws_size,
                              hipStream_t stream)
{
  const float* x     = (const float*)d_in[0];
  const int*   ei    = (const int*)d_in[1];   // [2, E] int32
  const int*   et    = (const int*)d_in[2];   // [E]
  const float* w1    = (const float*)d_in[3];
  const float* root1 = (const float*)d_in[4];
  const float* b1    = (const float*)d_in[5];
  const float* w2    = (const float*)d_in[6];
  const float* root2 = (const float*)d_in[7];
  const float* b2    = (const float*)d_in[8];
  const float* w3    = (const float*)d_in[9];
  const float* root3 = (const float*)d_in[10];
  const float* b3    = (const float*)d_in[11];
  float* out = (float*)d_out;

  const int* esrc = ei;
  const int* edst = ei + EE;

  char* w = (char*)d_ws;
  auto alloc = [&](size_t bytes)->char*{ char* p = w; w += (bytes + 255) & ~(size_t)255; return p; };
  int*   cnt   = (int*)  alloc((size_t)NRSEG * 4);
  int*   offs  = (int*)  alloc((size_t)(NRSEG + 1) * 4);
  int*   fill  = (int*)  alloc((size_t)NRSEG * 4);
  float* inv   = (float*)alloc((size_t)NRSEG * 4);
  int*   ssrc  = (int*)  alloc((size_t)EE * 4);
  u16*   xb    = (u16*)  alloc((size_t)NN * 128 * 2);
  u16*   h1b   = (u16*)  alloc((size_t)NN * 256 * 2);
  u16*   h2b   = (u16*)  alloc((size_t)NN * 128 * 2);
  u16*   wp1   = (u16*)  alloc((size_t)9 * 256 * 128 * 2);
  u16*   wp2   = (u16*)  alloc((size_t)9 * 256 * 128 * 2);
  u16*   wp3   = (u16*)  alloc((size_t)9 * 128 * 128 * 2);
  int*   bsums = (int*)  alloc(1024 * 4);
  u16*   agg   = (u16*)  alloc((size_t)NN * 1024 * 2);
  (void)ws_size; (void)in_sizes; (void)n_in; (void)out_size;

  hipMemsetAsync(cnt,  0, (size_t)NRSEG * 4, stream);
  hipMemsetAsync(fill, 0, (size_t)NRSEG * 4, stream);

  count_k<<<(EE + 255) / 256, 256, 0, stream>>>(edst, et, cnt);
  scan1_k<<<NB, 256, 0, stream>>>(cnt, bsums);
  scan2_k<<<1, 256, 0, stream>>>(bsums);
  scan3_k<<<NB, 256, 0, stream>>>(cnt, bsums, offs);
  fill_k<<<(EE + 255) / 256, 256, 0, stream>>>(esrc, edst, et, offs, fill, ssrc);
  inv_k<<<(NRSEG + 255) / 256, 256, 0, stream>>>(cnt, inv);
  castx_k<<<(NN * 128 + 255) / 256, 256, 0, stream>>>(x, xb);

  packw_k<<<(9 * 128 * 256 + 255) / 256, 256, 0, stream>>>(w1, root1, wp1, 128, 256);
  packw_k<<<(9 * 256 * 128 + 255) / 256, 256, 0, stream>>>(w2, root2, wp2, 256, 128);
  packw_k<<<(9 * 128 * 128 + 255) / 256, 256, 0, stream>>>(w3, root3, wp3, 128, 128);

  const int MT = (NN + 127) / 128;   // 391

  // Layer 1: fin=128, fout=256 (single 128x256 tile per block)
  agg_k<128, 8><<<4096, 256, 0, stream>>>(xb, ssrc, offs, inv, agg, 0);
  gemm_k<128, 8, true, 1, 256><<<MT, 512, 0, stream>>>(
      agg, xb, wp1, wp1 + (size_t)8 * 256 * 128, b1, out + 0, h1b);

  // Layer 2: fin=256, fout=128, split into two relation halves
  agg_k<256, 4><<<4096, 256, 0, stream>>>(h1b, ssrc, offs, inv, agg, 0);
  gemm_k<256, 4, true, 0, 128><<<MT, 512, 0, stream>>>(
      agg, h1b, wp2, wp2 + (size_t)8 * 128 * 256, nullptr, out + 256, nullptr);
  agg_k<256, 4><<<4096, 256, 0, stream>>>(h1b, ssrc, offs, inv, agg, 4);
  gemm_k<256, 4, false, 2, 128><<<MT, 512, 0, stream>>>(
      agg, nullptr, wp2 + (size_t)4 * 128 * 256, nullptr, b2, out + 256, h2b);

  // Layer 3: fin=128, fout=128
  agg_k<128, 8><<<4096, 256, 0, stream>>>(h2b, ssrc, offs, inv, agg, 0);
  gemm_k<128, 8, true, 1, 128><<<MT, 512, 0, stream>>>(
      agg, h2b, wp3, wp3 + (size_t)8 * 128 * 128, b3, out + 384, nullptr);
}